// Round 14
// baseline (156.225 us; speedup 1.0000x reference)
//
#include <hip/hip_runtime.h>

typedef unsigned int u32;
typedef unsigned long long u64;
typedef float v2f __attribute__((ext_vector_type(2)));
typedef float v8f __attribute__((ext_vector_type(8)));

#define NBATCH 8
#define NPTS   4096
#define NQTOT  (NBATCH * NPTS)   /* 32768 */
#define KNN    16
#define NBASIS 8
#define OUTM   64
#define NSPLIT 8
#define WIN    (NPTS / NSPLIT)   /* 512 candidates per window */
#define QPB    64
#define TKNN   (QPB * NSPLIT)    /* 512 threads = 8 waves */
#define GRP    16
/* CAPACITY MODEL (R12 failure lesson): thr is STATIC within a phase, so
 * per-phase admissions are Binomial(new_candidates, ~16/seen) — E=16/query
 * per DOUBLING phase. ECAP=64 = mean+13sigma. Doubling phases + cap 64
 * proven across R3/R5/R7/R10/R11/R13. */
#define ECAP   64
/* Admission margin: |approx_d2 - exact_d2| <= ~2e-5 at these magnitudes for
 * the fma-contracted forms used here; eps = 2e-4 gives 10x headroom.
 * Admission is a SUPERSET of the exact test; the digest recomputes exact d2
 * and discards extras -> selection bit-identical. Proven R10/R11/R13. */
#define THR_EPS 2e-4f
/* per-query LDS row (u64): [0,32) = 2 seed-funnel segments / 64-u32 entry
 * buffer / epilogue scratch; [32,48) = t16 (also 3rd funnel seg during seed);
 * [48] pad. 32 KB/block. */
#define ROWSTR 49
#define TOFF   32

// sentinel: d2 = +inf, idx = all-ones (sorts last)
#define SENT 0x7f800000ffffffffull

// Packed candidate records: per PAIR of candidates [x0 x1 y0 y1 z0 z1 h0 h1]
// (h = |c|^2/2). One s_load_dwordx8 feeds a pair's whole dot-chain+compare —
// 8 scalar loads per group-of-16 vs 32 with separate planes (R13). All v2f
// sub-pairs of the dwordx8 result are even-aligned SGPR pairs -> legal
// single-scalar operands for v_pk math (same constraint discipline as R11).
// Static device global (512 KB): statics proven safe (R9/R11); workspace
// stays at the proven 0.92 MB.
__device__ v8f g_pk8[NQTOT / 2];

__device__ __forceinline__ void ce(u64& x, u64& y) {
  u64 a = x, b = y;
  bool sw = b < a;
  x = sw ? b : a;
  y = sw ? a : b;
}

// Batcher odd-even mergesort network (fully unrolled).
template <int N>
__device__ __forceinline__ void oems_sort(u64* a) {
#pragma unroll
  for (int p = 1; p < N; p <<= 1) {
#pragma unroll
    for (int k = p; k >= 1; k >>= 1) {
#pragma unroll
      for (int j = k & (p - 1); j + k < N; j += 2 * k) {
#pragma unroll
        for (int i = 0; i < k; ++i) {
          int lo = i + j, hi = i + j + k;
          if (hi < N && (lo / (2 * p)) == (hi / (2 * p)))
            ce(a[lo], a[hi]);
        }
      }
    }
  }
}

// t, a sorted asc -> t = smallest 16 of union, sorted asc.
__device__ __forceinline__ void merge16(u64 t[16], const u64 a[16]) {
  u64 m[16];
#pragma unroll
  for (int i = 0; i < 16; ++i) {
    u64 x = t[i], y = a[15 - i];
    m[i] = (x < y) ? x : y;
  }
#pragma unroll
  for (int k = 8; k >= 1; k >>= 1) {
#pragma unroll
    for (int i = 0; i < 16; ++i) {
      if ((i & k) == 0) ce(m[i], m[i | k]);
    }
  }
#pragma unroll
  for (int i = 0; i < 16; ++i) t[i] = m[i];
}

// Bit-exact d2 pair: ((dx^2+dy^2)+dz^2), no FMA contraction. v_pk ops round
// IEEE-identically to scalar (verified bit-exact vs reference rounds 0-13).
// Used where d2 becomes a SORT KEY (seed). Input values from the packed
// layout are the SAME floats as the old planes -> keys bit-identical.
__device__ __forceinline__ v2f d2pair(v2f cx, v2f cy, v2f cz, v2f qx, v2f qy,
                                      v2f qz) {
#pragma clang fp contract(off)
  v2f dx = cx - qx;
  v2f dy = cy - qy;
  v2f dz = cz - qz;
  v2f d2 = (dx * dx + dy * dy) + dz * dz;
  return d2;
}

// Scalar bit-exact d2 (identical rounding to d2pair) — digest recompute.
// Proven bit-exact vs reference in rounds 1, 5, 6, 7, 10, 11, 13.
__device__ __forceinline__ float d2s(float cx, float cy, float cz, float qx,
                                     float qy, float qz) {
#pragma clang fp contract(off)
  float dx = cx - qx;
  float dy = cy - qy;
  float dz = cz - qz;
  return (dx * dx + dy * dy) + dz * dz;
}

// publish a sorted 16-list into funnel segment seg of this query's row
__device__ __forceinline__ void pub16(u64* row, int seg, const u64 s[16]) {
#pragma unroll
  for (int e = 0; e < 16; ++e) row[seg * 16 + e] = s[e];
}

// merge funnel segment seg into register list s
__device__ __forceinline__ void mrg16(const u64* row, int seg, u64 s[16]) {
  u64 a[16];
#pragma unroll
  for (int e = 0; e < 16; ++e) a[e] = row[seg * 16 + e];
  merge16(s, a);
}

// Fused kNN + tensor-product features — R13 structure (proven, 154.7us
// total): 512-thread blocks, 8 windows, 5 doubling phases, rotating
// single-wave digest, GRP=16 group-encoded entries, dot-space admission
// with rhs folded into the fma chain. R14 edit: packed xxyyzzhh candidate
// records -> one s_load_dwordx8 per pair (8 scalar loads/group vs 32),
// attacking SMEM issue count / in-order lgkmcnt tracking in the scan.
// Values identical to the plane layout -> all keys/admissions bit-exact.
// Lessons held: structure changes (R2/R6/R9/R12) regress; scan-issue cuts
// (R3/R5/R10/R11/R13) convert ~1:1. NO __launch_bounds__ min-waves.
__global__ __launch_bounds__(TKNN) void se3_kernel(
    const float* __restrict__ Xp, const float* __restrict__ Yp,
    const float* __restrict__ Zp, const float4* __restrict__ cpad,
    const float* __restrict__ Wmat, float* __restrict__ out) {
  __shared__ u64 sBuf[QPB * ROWSTR];  // 25.1 KB
  __shared__ u32 sCnt[QPB];
  __shared__ float sThr[QPB];
  __shared__ float sM[QPB * 25];      // reduced M[8][3], stride 25

  const int b = blockIdx.x;
  const int qg = blockIdx.y;
  const int tid = threadIdx.x;
  const int ql = tid & 63;
  const int sp = tid >> 6;  // window id, wave-uniform
  const int qi = qg * QPB + ql;
  const int base = b * NPTS;

  if (tid < QPB) sCnt[tid] = 0;

  // per-lane query coords (coalesced)
  const float qx = Xp[base + qi];
  const float qy = Yp[base + qi];
  const float qz = Zp[base + qi];
  const v2f qxx = {qx, qx}, qyy = {qy, qy}, qzz = {qz, qz};
  const float qn = qx * qx + qy * qy + qz * qz;

  // wave-uniform candidate window -> packed dwordx8 scalar loads
  const int wbase = __builtin_amdgcn_readfirstlane(sp * WIN);
  const v8f* pkw = g_pk8 + ((base + wbase) >> 1);  // pair records
  const int sj = qi - wbase;  // self position inside window (may be OOR)

  u64* row = sBuf + (size_t)ql * ROWSTR;

  // ---- Seed: every wave sorts its window's first 16; 3-seg tree merge ----
  // (exact d2 — these values become sort keys directly)
  {
    u64 s16[16];
    float cd[16];
#pragma unroll
    for (int p = 0; p < 8; ++p) {
      v8f P = pkw[p];
      v2f cx = {P[0], P[1]}, cy = {P[2], P[3]}, cz = {P[4], P[5]};
      v2f d2 = d2pair(cx, cy, cz, qxx, qyy, qzz);
      cd[2 * p + 0] = d2.x;
      cd[2 * p + 1] = d2.y;
    }
#pragma unroll
    for (int i = 0; i < 16; ++i) {
      u64 v = ((u64)__float_as_uint(cd[i]) << 32) | (u32)(wbase + i);
      s16[i] = (i == sj) ? SENT : v;
    }
    oems_sort<16>(s16);

    // P1: w5,w6,w7 -> segs 0,1,2 (seg2 = t16 region, free during seed)
    if (sp >= 5) pub16(row, sp - 5, s16);
    __syncthreads();
    if (sp >= 1 && sp <= 3) mrg16(row, sp - 1, s16);  // {1,5} {2,6} {3,7}
    __syncthreads();
    // P2: w4 -> seg0, w3 -> seg1
    if (sp == 4) pub16(row, 0, s16);
    if (sp == 3) pub16(row, 1, s16);
    __syncthreads();
    if (sp == 0) mrg16(row, 0, s16);  // {0,4}
    if (sp == 1) mrg16(row, 1, s16);  // {1,5,3,7}
    __syncthreads();
    // P3: w2 -> seg0, w1 -> seg1
    if (sp == 2) pub16(row, 0, s16);
    if (sp == 1) pub16(row, 1, s16);
    __syncthreads();
    if (sp == 0) {
      mrg16(row, 0, s16);  // {0,4,2,6}
      mrg16(row, 1, s16);  // all 8 windows
#pragma unroll
      for (int e = 0; e < 16; ++e) row[TOFF + e] = s16[e];
      sThr[ql] = __uint_as_float((u32)(s16[15] >> 32));
    }
    __syncthreads();
  }
  float thr = sThr[ql];
  // dot-space threshold: admit iff c.q + rhs >= H
  float rhs = 0.5f * (thr + THR_EPS - qn);
  v2f rhsv = {rhs, rhs};

  // self-exclusion mask precompute (GRP=16 groups)
  const int selfgrp = (sj >= 0 && sj < WIN) ? (sj >> 4) : -1;
  const u32 selfbit = 1u << (sj & 15);

  // entry buffer: u32 slots [0,64) of the row = u64 slots [0,32)
  u32* ebuf = (u32*)row;

  // ---- Main scan: 5 doubling phases; digest wave rotates (1..5) ----
#pragma unroll
  for (int ph = 0; ph < 5; ++ph) {
    const int cstart = 16 << ph;  // [16,32),[32,64),...,[256,512)
    const int cend = 32 << ph;
#pragma unroll 2
    for (int g = cstart; g < cend; g += GRP) {
      u32 want = 0;
#pragma unroll
      for (int p = 0; p < 8; ++p) {
        v8f P = pkw[(g >> 1) + p];
        v2f cx = {P[0], P[1]}, cy = {P[2], P[3]}, cz = {P[4], P[5]};
        v2f hh = {P[6], P[7]};
        v2f t1 = __builtin_elementwise_fma(cx, qxx, rhsv);  // 1 sgpr
        v2f t2 = __builtin_elementwise_fma(cy, qyy, t1);    // 1 sgpr
        v2f t3 = __builtin_elementwise_fma(cz, qzz, t2);    // 1 sgpr
        want |= (t3.x >= hh.x) ? (1u << (2 * p)) : 0u;      // 1 sgpr
        want |= (t3.y >= hh.y) ? (1u << (2 * p + 1)) : 0u;  // 1 sgpr
      }
      if ((g >> 4) == selfgrp) want &= ~selfbit;
      if (want) {  // ONE u32 entry per group-of-16 with any hit
        u32 slot = atomicAdd(&sCnt[ql], 1u);
        if (slot < ECAP) ebuf[slot] = (want << 12) | (u32)(wbase + g);
      }
    }
    __syncthreads();
    if (sp == ph + 1) {  // rotating digest wave (1..5), between barriers
      int n = (int)sCnt[ql];
      n = n < ECAP ? n : ECAP;
      if (__any(n > 0)) {
        u64 t16[16];
#pragma unroll
        for (int e = 0; e < 16; ++e) t16[e] = row[TOFF + e];
        int cursor = 0;
        u32 curWant = 0, curBase = 0;
        while (__any(cursor < n || curWant != 0)) {
          // pass 1: decode up to 16 candidate indices (VALU only)
          u32 kidx[16];
          u32 vmask = 0;
#pragma unroll
          for (int e = 0; e < 16; ++e) {
            if (curWant == 0 && cursor < n) {
              u32 ent = ebuf[cursor++];
              curWant = ent >> 12;
              curBase = ent & 0xFFFu;
            }
            if (curWant) {
              int bit = __ffs(curWant) - 1;
              curWant &= curWant - 1;
              kidx[e] = curBase + (u32)bit;
              vmask |= (1u << e);
            } else {
              kidx[e] = 0;
            }
          }
          // pass 2: batched gathers + bit-exact d2 recompute
          u64 a[16];
#pragma unroll
          for (int e = 0; e < 16; ++e) {
            float4 c = cpad[base + (int)kidx[e]];
            float d2 = d2s(c.x, c.y, c.z, qx, qy, qz);
            u64 key = ((u64)__float_as_uint(d2) << 32) | kidx[e];
            a[e] = (vmask & (1u << e)) ? key : SENT;
          }
          oems_sort<16>(a);
          merge16(t16, a);
        }
#pragma unroll
        for (int e = 0; e < 16; ++e) row[TOFF + e] = t16[e];
        sThr[ql] = __uint_as_float((u32)(t16[15] >> 32));
      }
      sCnt[ql] = 0;
    }
    __syncthreads();
    thr = sThr[ql];
    rhs = 0.5f * (thr + THR_EPS - qn);
    rhsv.x = rhs;
    rhsv.y = rhs;
  }

  // ---- Epilogue phase 1 (waves 0-3): partial M over 4 neighbors each ----
  // pv is read by ALL participating threads first; the barrier then orders
  // those reads before scratch writes clobber the t16 region (row floats
  // [0,96) = the whole row incl. t16 floats [64,96), all dead afterward).
  u64 pv[4];
  if (sp < 4) {
#pragma unroll
    for (int e = 0; e < 4; ++e) pv[e] = row[TOFF + sp * 4 + e];
  }
  __syncthreads();
  if (sp < 4) {
    const int k = sp;
    float4 nc[4];
    float dd[4];
#pragma unroll
    for (int e = 0; e < 4; ++e) {
      nc[e] = cpad[base + (int)(u32)pv[e]];  // independent gathers
      dd[e] = __uint_as_float((u32)(pv[e] >> 32));
    }
    float M[24];
#pragma unroll
    for (int j = 0; j < 24; ++j) M[j] = 0.f;
#pragma unroll
    for (int e = 0; e < 4; ++e) {
      float rx = nc[e].x - qx;  // sender - receiver
      float ry = nc[e].y - qy;
      float rz = nc[e].z - qz;
      float dist = sqrtf(dd[e]);
      float inv = 1.0f / (dist + 1e-8f);
      rx *= inv; ry *= inv; rz *= inv;
      float cut = fminf(dist * 0.1f, 1.0f);
      float g[NBASIS], s = 0.f;
#pragma unroll
      for (int v = 0; v < NBASIS; ++v) {
        float t = cut - (float)v * (1.0f / 7.0f);
        g[v] = __expf(-32.0f * t * t);  // sigma = 1/8 -> 1/(2s^2) = 32
        s += g[v];
      }
      float rs = 1.0f / s;
#pragma unroll
      for (int v = 0; v < NBASIS; ++v) {
        float rb = g[v] * rs;
        M[v * 3 + 0] = fmaf(rb, rx, M[v * 3 + 0]);
        M[v * 3 + 1] = fmaf(rb, ry, M[v * 3 + 1]);
        M[v * 3 + 2] = fmaf(rb, rz, M[v * 3 + 2]);
      }
    }
    float* fp = (float*)row;
#pragma unroll
    for (int c = 0; c < 24; ++c) fp[k * 24 + c] = M[c];  // floats [0,96)
  }
  __syncthreads();

  // ---- Reduce partials: thread (q = ql, comps sp*3..sp*3+2) ----
  {
    const float* fp = (const float*)row;
#pragma unroll
    for (int j0 = 0; j0 < 3; ++j0) {
      int j = sp * 3 + j0;
      float s = fp[0 * 24 + j] + fp[1 * 24 + j] + fp[2 * 24 + j] +
                fp[3 * 24 + j];
      sM[ql * 25 + j] = s;
    }
  }
  __syncthreads();

  // ---- Epilogue phase 2 (all waves): out[q][w*3+m], lane w = ql ----
  float wreg[NBASIS];
#pragma unroll
  for (int v = 0; v < NBASIS; ++v) wreg[v] = Wmat[v * OUTM + ql];
  const float scale = 0.022097086912079608f;  // (1/sqrt(8)) / 16
#pragma unroll
  for (int i = 0; i < 8; ++i) {
    int q = sp * 8 + i;  // wave-uniform -> sM broadcasts
    const float* mq = sM + q * 25;
    float a0 = 0.f, a1 = 0.f, a2 = 0.f;
#pragma unroll
    for (int v = 0; v < NBASIS; ++v) {
      a0 = fmaf(wreg[v], mq[v * 3 + 0], a0);
      a1 = fmaf(wreg[v], mq[v * 3 + 1], a1);
      a2 = fmaf(wreg[v], mq[v * 3 + 2], a2);
    }
    size_t o = (size_t)(base + qg * QPB + q) * (OUTM * 3) + ql * 3;
    out[o + 0] = a0 * scale;
    out[o + 1] = a1 * scale;
    out[o + 2] = a2 * scale;
  }
}

// coords [B*N][3] -> x/y/z planes + float4 array + packed pair records.
__global__ void prep_kernel(const float* __restrict__ coords,
                            float* __restrict__ Xp, float* __restrict__ Yp,
                            float* __restrict__ Zp, float4* __restrict__ cpad) {
  int i = blockIdx.x * 256 + threadIdx.x;
  if (i < NQTOT) {
    float x = coords[3 * i + 0];
    float y = coords[3 * i + 1];
    float z = coords[3 * i + 2];
    Xp[i] = x; Yp[i] = y; Zp[i] = z;
    cpad[i] = make_float4(x, y, z, 0.f);
    float h = 0.5f * (x * x + y * y + z * z);
    // packed pair record [x0 x1 y0 y1 z0 z1 h0 h1]
    float* pk = (float*)g_pk8 + (size_t)(i >> 1) * 8;
    int l = i & 1;
    pk[0 + l] = x;
    pk[2 + l] = y;
    pk[4 + l] = z;
    pk[6 + l] = h;
  }
}

extern "C" void kernel_launch(void* const* d_in, const int* in_sizes, int n_in,
                              void* d_out, int out_size, void* d_ws, size_t ws_size,
                              hipStream_t stream) {
  const float* coords = (const float*)d_in[0];
  const float* Wmat = (const float*)d_in[1];
  float* out = (float*)d_out;

  char* w = (char*)d_ws;
  float* Xp = (float*)(w);               // 128 KB
  float* Yp = (float*)(w + 131072);
  float* Zp = (float*)(w + 262144);
  float4* cpad = (float4*)(w + 393216);  // 512 KB; ws use = 0.92 MB (proven)

  prep_kernel<<<dim3((NQTOT + 255) / 256), dim3(256), 0, stream>>>(coords, Xp, Yp, Zp, cpad);
  se3_kernel<<<dim3(NBATCH, NPTS / QPB), dim3(TKNN), 0, stream>>>(Xp, Yp, Zp, cpad, Wmat, out);
}

// Round 17
// 154.118 us; speedup vs baseline: 1.0137x; 1.0137x over previous
//
#include <hip/hip_runtime.h>

typedef unsigned int u32;
typedef unsigned long long u64;
typedef float v2f __attribute__((ext_vector_type(2)));

#define NBATCH 8
#define NPTS   4096
#define NQTOT  (NBATCH * NPTS)   /* 32768 */
#define KNN    16
#define NBASIS 8
#define OUTM   64
#define NSPLIT 8
#define WIN    (NPTS / NSPLIT)   /* 512 candidates per window */
#define QPB    64
#define TKNN   (QPB * NSPLIT)    /* 512 threads = 8 waves */
#define NPH    6                 /* scan phases, explicit table below */
/* Entry cap in u64 slots. Deterministic bound over ALL 8 windows:
 * entries/phase <= 8 x {1,1,2,4,4,4} groups = {8,8,16,32,32,32} <= 32.
 * (R15 failed counting one window; R16 failed on a phase-range FORMULA
 * typo — ph=5 scanned [512,640) instead of [384,512). Fix: literal
 * tables, hand-verified: union covers [16,512) exactly once.) */
#define ECAP64 32
/* Admission margin: |approx_d2 - exact_d2| <= ~2e-5 at these magnitudes;
 * eps = 2e-4 gives 10x headroom. Admission is a SUPERSET of the exact
 * test; digest recomputes exact d2 and discards extras -> selection
 * bit-identical. Proven R10/R11/R13. Phase-splitting only TIGHTENS thr
 * mid-way -> still a superset. */
#define THR_EPS 2e-4f
/* per-query LDS row (u64): [0,32) = 2 seed-funnel segments / 32-u64 entry
 * buffer / epilogue scratch; [32,48) = t16 (also 3rd funnel seg during
 * seed); [48] pad. 32 KB/block. */
#define ROWSTR 49
#define TOFF   32

// sentinel: d2 = +inf, idx = all-ones (sorts last)
#define SENT 0x7f800000ffffffffull

// Half-squared-norm plane H[i] = |c_i|^2 / 2. Static device global (128 KB):
// no workspace growth; statics proven safe (R9/R11/R13).
__device__ float g_H[NQTOT];

__device__ __forceinline__ void ce(u64& x, u64& y) {
  u64 a = x, b = y;
  bool sw = b < a;
  x = sw ? b : a;
  y = sw ? a : b;
}

// Batcher odd-even mergesort network (fully unrolled).
template <int N>
__device__ __forceinline__ void oems_sort(u64* a) {
#pragma unroll
  for (int p = 1; p < N; p <<= 1) {
#pragma unroll
    for (int k = p; k >= 1; k >>= 1) {
#pragma unroll
      for (int j = k & (p - 1); j + k < N; j += 2 * k) {
#pragma unroll
        for (int i = 0; i < k; ++i) {
          int lo = i + j, hi = i + j + k;
          if (hi < N && (lo / (2 * p)) == (hi / (2 * p)))
            ce(a[lo], a[hi]);
        }
      }
    }
  }
}

// t, a sorted asc -> t = smallest 16 of union, sorted asc.
__device__ __forceinline__ void merge16(u64 t[16], const u64 a[16]) {
  u64 m[16];
#pragma unroll
  for (int i = 0; i < 16; ++i) {
    u64 x = t[i], y = a[15 - i];
    m[i] = (x < y) ? x : y;
  }
#pragma unroll
  for (int k = 8; k >= 1; k >>= 1) {
#pragma unroll
    for (int i = 0; i < 16; ++i) {
      if ((i & k) == 0) ce(m[i], m[i | k]);
    }
  }
#pragma unroll
  for (int i = 0; i < 16; ++i) t[i] = m[i];
}

// Bit-exact d2 pair: ((dx^2+dy^2)+dz^2), no FMA contraction. v_pk ops round
// IEEE-identically to scalar (verified bit-exact vs reference rounds 0-14).
// Used where d2 becomes a SORT KEY (seed).
__device__ __forceinline__ v2f d2pair(v2f cx, v2f cy, v2f cz, v2f qx, v2f qy,
                                      v2f qz) {
#pragma clang fp contract(off)
  v2f dx = cx - qx;
  v2f dy = cy - qy;
  v2f dz = cz - qz;
  v2f d2 = (dx * dx + dy * dy) + dz * dz;
  return d2;
}

// Scalar bit-exact d2 (identical rounding to d2pair) — digest recompute.
// Proven bit-exact vs reference in rounds 1, 5, 6, 7, 10, 11, 13, 14.
__device__ __forceinline__ float d2s(float cx, float cy, float cz, float qx,
                                     float qy, float qz) {
#pragma clang fp contract(off)
  float dx = cx - qx;
  float dy = cy - qy;
  float dz = cz - qz;
  return (dx * dx + dy * dy) + dz * dz;
}

// publish a sorted 16-list into funnel segment seg of this query's row
__device__ __forceinline__ void pub16(u64* row, int seg, const u64 s[16]) {
#pragma unroll
  for (int e = 0; e < 16; ++e) row[seg * 16 + e] = s[e];
}

// merge funnel segment seg into register list s
__device__ __forceinline__ void mrg16(const u64* row, int seg, u64 s[16]) {
  u64 a[16];
#pragma unroll
  for (int e = 0; e < 16; ++e) a[e] = row[seg * 16 + e];
  merge16(s, a);
}

// Fused kNN + tensor-product features — R13 structure + GRP=32 scan.
// Phases (LITERAL table, hand-verified): [16,32) 16-wide, then 32-wide
// groups over [32,64),[64,128),[128,256),[256,384),[384,512). Last phase
// split keeps the per-query entry count deterministically <= 32 across all
// 8 windows. GRP=32 halves per-group fixed overhead (self check, want
// branch, atomic path) vs R13's 16. u64 entries ((u64)want32<<32 | base).
// Rotating single-wave digest (waves 1..6). Lessons held: structure
// changes (R2/R6/R9/R12) regress; scan-issue cuts (R3/R5/R10/R11/R13)
// convert ~1:1; load plumbing not binding (R14). NO __launch_bounds__
// min-waves (spills, measured).
__global__ __launch_bounds__(TKNN) void se3_kernel(
    const float* __restrict__ Xp, const float* __restrict__ Yp,
    const float* __restrict__ Zp, const float4* __restrict__ cpad,
    const float* __restrict__ Wmat, float* __restrict__ out) {
  __shared__ u64 sBuf[QPB * ROWSTR];  // 25.1 KB
  __shared__ u32 sCnt[QPB];
  __shared__ float sThr[QPB];
  __shared__ float sM[QPB * 25];      // reduced M[8][3], stride 25

  const int b = blockIdx.x;
  const int qg = blockIdx.y;
  const int tid = threadIdx.x;
  const int ql = tid & 63;
  const int sp = tid >> 6;  // window id, wave-uniform
  const int qi = qg * QPB + ql;
  const int base = b * NPTS;

  if (tid < QPB) sCnt[tid] = 0;

  // per-lane query coords (coalesced)
  const float qx = Xp[base + qi];
  const float qy = Yp[base + qi];
  const float qz = Zp[base + qi];
  const v2f qxx = {qx, qx}, qyy = {qy, qy}, qzz = {qz, qz};
  const float qn = qx * qx + qy * qy + qz * qz;

  // wave-uniform candidate window -> scalar loads feeding packed math
  const int wbase = __builtin_amdgcn_readfirstlane(sp * WIN);
  const v2f* xs2 = (const v2f*)(Xp + base + wbase);
  const v2f* ys2 = (const v2f*)(Yp + base + wbase);
  const v2f* zs2 = (const v2f*)(Zp + base + wbase);
  const v2f* hs2 = (const v2f*)(g_H + base + wbase);
  const int sj = qi - wbase;  // self position inside window (may be OOR)

  u64* row = sBuf + (size_t)ql * ROWSTR;

  // ---- Seed: every wave sorts its window's first 16; 3-seg tree merge ----
  // (exact d2 — these values become sort keys directly)
  {
    u64 s16[16];
    float cd[16];
#pragma unroll
    for (int p = 0; p < 8; ++p) {
      v2f d2 = d2pair(xs2[p], ys2[p], zs2[p], qxx, qyy, qzz);
      cd[2 * p + 0] = d2.x;
      cd[2 * p + 1] = d2.y;
    }
#pragma unroll
    for (int i = 0; i < 16; ++i) {
      u64 v = ((u64)__float_as_uint(cd[i]) << 32) | (u32)(wbase + i);
      s16[i] = (i == sj) ? SENT : v;
    }
    oems_sort<16>(s16);

    // P1: w5,w6,w7 -> segs 0,1,2 (seg2 = t16 region, free during seed)
    if (sp >= 5) pub16(row, sp - 5, s16);
    __syncthreads();
    if (sp >= 1 && sp <= 3) mrg16(row, sp - 1, s16);  // {1,5} {2,6} {3,7}
    __syncthreads();
    // P2: w4 -> seg0, w3 -> seg1
    if (sp == 4) pub16(row, 0, s16);
    if (sp == 3) pub16(row, 1, s16);
    __syncthreads();
    if (sp == 0) mrg16(row, 0, s16);  // {0,4}
    if (sp == 1) mrg16(row, 1, s16);  // {1,5,3,7}
    __syncthreads();
    // P3: w2 -> seg0, w1 -> seg1
    if (sp == 2) pub16(row, 0, s16);
    if (sp == 1) pub16(row, 1, s16);
    __syncthreads();
    if (sp == 0) {
      mrg16(row, 0, s16);  // {0,4,2,6}
      mrg16(row, 1, s16);  // all 8 windows
#pragma unroll
      for (int e = 0; e < 16; ++e) row[TOFF + e] = s16[e];
      sThr[ql] = __uint_as_float((u32)(s16[15] >> 32));
    }
    __syncthreads();
  }
  float thr = sThr[ql];
  // dot-space threshold: admit iff c.q + rhs >= H
  float rhs = 0.5f * (thr + THR_EPS - qn);
  v2f rhsv = {rhs, rhs};

  // self-exclusion mask precompute (phase0 uses a 16-group, rest 32-groups)
  const int selfg16 = (sj >= 0 && sj < WIN) ? (sj >> 4) : -1;
  const int selfg32 = (sj >= 0 && sj < WIN) ? (sj >> 5) : -1;

  // entry buffer: u64 slots [0,32) of the row
  u64* ebuf = row;

  // ---- Main scan: 6 phases (literal table); digest rotates (1..6) ----
  const int phs[NPH] = {16, 32, 64, 128, 256, 384};
  const int phe[NPH] = {32, 64, 128, 256, 384, 512};
#pragma unroll
  for (int ph = 0; ph < NPH; ++ph) {
    if (ph == 0) {
      // phase 0: candidates [16,32) — one 16-wide group
      u32 want = 0;
#pragma unroll
      for (int p = 0; p < 8; ++p) {
        const int ix = 8 + p;
        v2f t1 = __builtin_elementwise_fma(xs2[ix], qxx, rhsv);  // 1 sgpr
        v2f t2 = __builtin_elementwise_fma(ys2[ix], qyy, t1);    // 1 sgpr
        v2f t3 = __builtin_elementwise_fma(zs2[ix], qzz, t2);    // 1 sgpr
        want |= (t3.x >= hs2[ix].x) ? (1u << (2 * p)) : 0u;      // 1 sgpr
        want |= (t3.y >= hs2[ix].y) ? (1u << (2 * p + 1)) : 0u;  // 1 sgpr
      }
      if (selfg16 == 1) want &= ~(1u << (sj & 15));
      if (want) {
        u32 slot = atomicAdd(&sCnt[ql], 1u);
        if (slot < ECAP64) ebuf[slot] = ((u64)want << 32) | (u32)(wbase + 16);
      }
    } else {
      const int cstart = phs[ph];
      const int cend = phe[ph];
#pragma unroll 2
      for (int g = cstart; g < cend; g += 32) {
        u32 want = 0;
#pragma unroll
        for (int p = 0; p < 16; ++p) {
          const int ix = (g >> 1) + p;
          v2f t1 = __builtin_elementwise_fma(xs2[ix], qxx, rhsv);
          v2f t2 = __builtin_elementwise_fma(ys2[ix], qyy, t1);
          v2f t3 = __builtin_elementwise_fma(zs2[ix], qzz, t2);
          want |= (t3.x >= hs2[ix].x) ? (1u << (2 * p)) : 0u;
          want |= (t3.y >= hs2[ix].y) ? (1u << (2 * p + 1)) : 0u;
        }
        if ((g >> 5) == selfg32) want &= ~(1u << (sj & 31));
        if (want) {  // ONE u64 entry per group-of-32 with any hit
          u32 slot = atomicAdd(&sCnt[ql], 1u);
          if (slot < ECAP64) ebuf[slot] = ((u64)want << 32) | (u32)(wbase + g);
        }
      }
    }
    __syncthreads();
    if (sp == ph + 1) {  // rotating digest wave (1..6), between barriers
      int n = (int)sCnt[ql];
      n = n < ECAP64 ? n : ECAP64;
      if (__any(n > 0)) {
        u64 t16[16];
#pragma unroll
        for (int e = 0; e < 16; ++e) t16[e] = row[TOFF + e];
        int cursor = 0;
        u32 curWant = 0, curBase = 0;
        while (__any(cursor < n || curWant != 0)) {
          // pass 1: decode up to 16 candidate indices (VALU only)
          u32 kidx[16];
          u32 vmask = 0;
#pragma unroll
          for (int e = 0; e < 16; ++e) {
            if (curWant == 0 && cursor < n) {
              u64 ent = ebuf[cursor++];
              curWant = (u32)(ent >> 32);
              curBase = (u32)ent & 0xFFFu;
            }
            if (curWant) {
              int bit = __ffs(curWant) - 1;
              curWant &= curWant - 1;
              kidx[e] = curBase + (u32)bit;
              vmask |= (1u << e);
            } else {
              kidx[e] = 0;
            }
          }
          // pass 2: batched gathers + bit-exact d2 recompute
          u64 a[16];
#pragma unroll
          for (int e = 0; e < 16; ++e) {
            float4 c = cpad[base + (int)kidx[e]];
            float d2 = d2s(c.x, c.y, c.z, qx, qy, qz);
            u64 key = ((u64)__float_as_uint(d2) << 32) | kidx[e];
            a[e] = (vmask & (1u << e)) ? key : SENT;
          }
          oems_sort<16>(a);
          merge16(t16, a);
        }
#pragma unroll
        for (int e = 0; e < 16; ++e) row[TOFF + e] = t16[e];
        sThr[ql] = __uint_as_float((u32)(t16[15] >> 32));
      }
      sCnt[ql] = 0;
    }
    __syncthreads();
    thr = sThr[ql];
    rhs = 0.5f * (thr + THR_EPS - qn);
    rhsv.x = rhs;
    rhsv.y = rhs;
  }

  // ---- Epilogue phase 1 (waves 0-3): partial M over 4 neighbors each ----
  // pv is read by ALL participating threads first; the barrier then orders
  // those reads before scratch writes clobber the t16 region (row floats
  // [0,96) = the whole row incl. t16 floats [64,96), all dead afterward).
  u64 pv[4];
  if (sp < 4) {
#pragma unroll
    for (int e = 0; e < 4; ++e) pv[e] = row[TOFF + sp * 4 + e];
  }
  __syncthreads();
  if (sp < 4) {
    const int k = sp;
    float4 nc[4];
    float dd[4];
#pragma unroll
    for (int e = 0; e < 4; ++e) {
      nc[e] = cpad[base + (int)(u32)pv[e]];  // independent gathers
      dd[e] = __uint_as_float((u32)(pv[e] >> 32));
    }
    float M[24];
#pragma unroll
    for (int j = 0; j < 24; ++j) M[j] = 0.f;
#pragma unroll
    for (int e = 0; e < 4; ++e) {
      float rx = nc[e].x - qx;  // sender - receiver
      float ry = nc[e].y - qy;
      float rz = nc[e].z - qz;
      float dist = sqrtf(dd[e]);
      float inv = 1.0f / (dist + 1e-8f);
      rx *= inv; ry *= inv; rz *= inv;
      float cut = fminf(dist * 0.1f, 1.0f);
      float g[NBASIS], s = 0.f;
#pragma unroll
      for (int v = 0; v < NBASIS; ++v) {
        float t = cut - (float)v * (1.0f / 7.0f);
        g[v] = __expf(-32.0f * t * t);  // sigma = 1/8 -> 1/(2s^2) = 32
        s += g[v];
      }
      float rs = 1.0f / s;
#pragma unroll
      for (int v = 0; v < NBASIS; ++v) {
        float rb = g[v] * rs;
        M[v * 3 + 0] = fmaf(rb, rx, M[v * 3 + 0]);
        M[v * 3 + 1] = fmaf(rb, ry, M[v * 3 + 1]);
        M[v * 3 + 2] = fmaf(rb, rz, M[v * 3 + 2]);
      }
    }
    float* fp = (float*)row;
#pragma unroll
    for (int c = 0; c < 24; ++c) fp[k * 24 + c] = M[c];  // floats [0,96)
  }
  __syncthreads();

  // ---- Reduce partials: thread (q = ql, comps sp*3..sp*3+2) ----
  {
    const float* fp = (const float*)row;
#pragma unroll
    for (int j0 = 0; j0 < 3; ++j0) {
      int j = sp * 3 + j0;
      float s = fp[0 * 24 + j] + fp[1 * 24 + j] + fp[2 * 24 + j] +
                fp[3 * 24 + j];
      sM[ql * 25 + j] = s;
    }
  }
  __syncthreads();

  // ---- Epilogue phase 2 (all waves): out[q][w*3+m], lane w = ql ----
  float wreg[NBASIS];
#pragma unroll
  for (int v = 0; v < NBASIS; ++v) wreg[v] = Wmat[v * OUTM + ql];
  const float scale = 0.022097086912079608f;  // (1/sqrt(8)) / 16
#pragma unroll
  for (int i = 0; i < 8; ++i) {
    int q = sp * 8 + i;  // wave-uniform -> sM broadcasts
    const float* mq = sM + q * 25;
    float a0 = 0.f, a1 = 0.f, a2 = 0.f;
#pragma unroll
    for (int v = 0; v < NBASIS; ++v) {
      a0 = fmaf(wreg[v], mq[v * 3 + 0], a0);
      a1 = fmaf(wreg[v], mq[v * 3 + 1], a1);
      a2 = fmaf(wreg[v], mq[v * 3 + 2], a2);
    }
    size_t o = (size_t)(base + qg * QPB + q) * (OUTM * 3) + ql * 3;
    out[o + 0] = a0 * scale;
    out[o + 1] = a1 * scale;
    out[o + 2] = a2 * scale;
  }
}

// coords [B*N][3] -> x/y/z planes + float4 array + half-norm plane.
__global__ void prep_kernel(const float* __restrict__ coords,
                            float* __restrict__ Xp, float* __restrict__ Yp,
                            float* __restrict__ Zp, float4* __restrict__ cpad) {
  int i = blockIdx.x * 256 + threadIdx.x;
  if (i < NQTOT) {
    float x = coords[3 * i + 0];
    float y = coords[3 * i + 1];
    float z = coords[3 * i + 2];
    Xp[i] = x; Yp[i] = y; Zp[i] = z;
    cpad[i] = make_float4(x, y, z, 0.f);
    g_H[i] = 0.5f * (x * x + y * y + z * z);
  }
}

extern "C" void kernel_launch(void* const* d_in, const int* in_sizes, int n_in,
                              void* d_out, int out_size, void* d_ws, size_t ws_size,
                              hipStream_t stream) {
  const float* coords = (const float*)d_in[0];
  const float* Wmat = (const float*)d_in[1];
  float* out = (float*)d_out;

  char* w = (char*)d_ws;
  float* Xp = (float*)(w);               // 128 KB
  float* Yp = (float*)(w + 131072);
  float* Zp = (float*)(w + 262144);
  float4* cpad = (float4*)(w + 393216);  // 512 KB; ws use = 0.92 MB (proven)

  prep_kernel<<<dim3((NQTOT + 255) / 256), dim3(256), 0, stream>>>(coords, Xp, Yp, Zp, cpad);
  se3_kernel<<<dim3(NBATCH, NPTS / QPB), dim3(TKNN), 0, stream>>>(Xp, Yp, Zp, cpad, Wmat, out);
}